// Round 2
// baseline (1789.712 us; speedup 1.0000x reference)
//
#include <hip/hip_runtime.h>
#include <hip/hip_bf16.h>
#include <limits.h>

#define NSEG 200
#define STRENGTH 1e-3f
#define WCAP 1024   // LDS window capacity (floats); worst-case window ~ 256 + 2*max_bucket ~ 380

__device__ __forceinline__ int bucket_of(float x, int B, float scale) {
    float t = (x + 6.0f) * scale;   // scale = B/12
    int b = (int)floorf(t);
    b = b < 0 ? 0 : (b > B - 1 ? B - 1 : b);
    return b;
}

// ---- 1. histogram of (segment, bucket), float4/int4 loads ----
__global__ void k_hist(const float* __restrict__ x, const int* __restrict__ seg,
                       int* __restrict__ counts, int N, int B, float scale) {
    int stride = gridDim.x * blockDim.x;
    int tid = blockIdx.x * blockDim.x + threadIdx.x;
    int N4 = N >> 2;
    const float4* x4 = (const float4*)x;
    const int4* s4 = (const int4*)seg;
    for (int i = tid; i < N4; i += stride) {
        float4 v = x4[i]; int4 s = s4[i];
        atomicAdd(&counts[s.x * B + bucket_of(v.x, B, scale)], 1);
        atomicAdd(&counts[s.y * B + bucket_of(v.y, B, scale)], 1);
        atomicAdd(&counts[s.z * B + bucket_of(v.z, B, scale)], 1);
        atomicAdd(&counts[s.w * B + bucket_of(v.w, B, scale)], 1);
    }
    for (int i = (N4 << 2) + tid; i < N; i += stride)
        atomicAdd(&counts[seg[i] * B + bucket_of(x[i], B, scale)], 1);
}

// ---- 2. exclusive scan over M = NSEG*B counters (3 kernels, TILE=2048) ----
__global__ void k_scan_partial(const int* __restrict__ counts, int* __restrict__ partials, int M) {
    __shared__ int sdata[256];
    int base = blockIdx.x * 2048;
    int sum = 0;
    for (int k = threadIdx.x; k < 2048; k += 256) {
        int idx = base + k;
        sum += (idx < M) ? counts[idx] : 0;
    }
    sdata[threadIdx.x] = sum;
    __syncthreads();
    for (int off = 128; off > 0; off >>= 1) {
        if (threadIdx.x < off) sdata[threadIdx.x] += sdata[threadIdx.x + off];
        __syncthreads();
    }
    if (threadIdx.x == 0) partials[blockIdx.x] = sdata[0];
}

__global__ void k_scan_carry(int* __restrict__ partials, int nb) {
    __shared__ int bufA[1024], bufB[1024];
    int t = threadIdx.x;
    int v = (t < nb) ? partials[t] : 0;
    int* src = bufA; int* dst = bufB;
    src[t] = v;
    __syncthreads();
    for (int off = 1; off < 1024; off <<= 1) {
        dst[t] = src[t] + ((t >= off) ? src[t - off] : 0);
        __syncthreads();
        int* tmp = src; src = dst; dst = tmp;
    }
    if (t < nb) partials[t] = src[t] - v;   // exclusive
}

__global__ void k_scan_final(const int* __restrict__ counts, const int* __restrict__ partials,
                             int* __restrict__ cursor, int M) {
    __shared__ int tile[2048];
    __shared__ int sa[256], sb[256];
    int t = threadIdx.x;
    int base = blockIdx.x * 2048;
    for (int k = t; k < 2048; k += 256) {
        int idx = base + k;
        tile[k] = (idx < M) ? counts[idx] : 0;
    }
    __syncthreads();
    int loc[8]; int run = 0;
    for (int k = 0; k < 8; ++k) { loc[k] = run; run += tile[t * 8 + k]; }
    int v = run;
    int* src = sa; int* dst = sb;
    src[t] = v;
    __syncthreads();
    for (int off = 1; off < 256; off <<= 1) {
        dst[t] = src[t] + ((t >= off) ? src[t - off] : 0);
        __syncthreads();
        int* tmp = src; src = dst; dst = tmp;
    }
    int texcl = src[t] - v;
    int gbase = partials[blockIdx.x];
    for (int k = 0; k < 8; ++k) {
        int idx = base + t * 8 + k;
        if (idx < M) cursor[idx] = gbase + texcl + loc[k];
    }
}

// ---- 3. scatter into bucket-grouped order (non-stable; cursor becomes "ends") ----
__global__ void k_scatter(const float* __restrict__ x, const int* __restrict__ seg,
                          int* __restrict__ cursor, float* __restrict__ sx,
                          int N, int B, float scale) {
    int stride = gridDim.x * blockDim.x;
    int tid = blockIdx.x * blockDim.x + threadIdx.x;
    int N4 = N >> 2;
    const float4* x4 = (const float4*)x;
    const int4* s4 = (const int4*)seg;
    for (int i = tid; i < N4; i += stride) {
        float4 v = x4[i]; int4 s = s4[i];
        int p0 = atomicAdd(&cursor[s.x * B + bucket_of(v.x, B, scale)], 1); sx[p0] = v.x;
        int p1 = atomicAdd(&cursor[s.y * B + bucket_of(v.y, B, scale)], 1); sx[p1] = v.y;
        int p2 = atomicAdd(&cursor[s.z * B + bucket_of(v.z, B, scale)], 1); sx[p2] = v.z;
        int p3 = atomicAdd(&cursor[s.w * B + bucket_of(v.w, B, scale)], 1); sx[p3] = v.w;
    }
    for (int i = (N4 << 2) + tid; i < N; i += stride) {
        float v = x[i];
        int pos = atomicAdd(&cursor[seg[i] * B + bucket_of(v, B, scale)], 1);
        sx[pos] = v;
    }
}

// ---- 3b. compact per-segment end positions (reads post-scatter cursor == ends) ----
__global__ void k_segends(const int* __restrict__ ends, int* __restrict__ seg_ends, int B) {
    int t = blockIdx.x * blockDim.x + threadIdx.x;
    if (t < NSEG) seg_ends[t] = ends[(t + 1) * B - 1];
}

// ---- 4. rank within bucket via LDS-staged window -> |diff|, per-segment sums ----
__global__ void __launch_bounds__(256)
k_emd(const float* __restrict__ sx, const float* __restrict__ y,
      const int* __restrict__ ends, const int* __restrict__ seg_ends,
      float* __restrict__ segSums, int N, int B, float scale) {
    __shared__ float win[WCAP];
    __shared__ int sseg[NSEG];
    __shared__ int rmin[256], rmax[256];
    int tid = threadIdx.x;
    for (int k = tid; k < NSEG; k += 256) sseg[k] = seg_ends[k];
    __syncthreads();

    int p = blockIdx.x * 256 + tid;
    float v = 0.f;
    int s = INT_MAX, start = INT_MAX, end = 0;
    if (p < N) {
        v = sx[p];
        int lo = 0, hi = NSEG - 1;
        while (lo < hi) { int mid = (lo + hi) >> 1; if (p < sseg[mid]) hi = mid; else lo = mid + 1; }
        s = lo;
        int g = s * B + bucket_of(v, B, scale);
        start = (g == 0) ? 0 : ends[g - 1];
        end = ends[g];
    }
    rmin[tid] = start; rmax[tid] = end;
    __syncthreads();
    for (int off = 128; off > 0; off >>= 1) {
        if (tid < off) {
            rmin[tid] = min(rmin[tid], rmin[tid + off]);
            rmax[tid] = max(rmax[tid], rmax[tid + off]);
        }
        __syncthreads();
    }
    int wlo = rmin[0], whi = rmax[0];
    bool lds = (wlo != INT_MAX) && (whi - wlo) <= WCAP;
    if (lds) {
        for (int k = tid; k < whi - wlo; k += 256) win[k] = sx[wlo + k];
    }
    __syncthreads();

    float diff = 0.f;
    if (p < N) {
        int rank = 0;
        if (lds) {
            int a = start - wlo, b = end - wlo, pk = p - wlo;
            int k = a;
            for (; k + 3 < b; k += 4) {
                float v0 = win[k], v1 = win[k + 1], v2 = win[k + 2], v3 = win[k + 3];
                rank += (v0 < v) || (v0 == v && (k)     < pk);
                rank += (v1 < v) || (v1 == v && (k + 1) < pk);
                rank += (v2 < v) || (v2 == v && (k + 2) < pk);
                rank += (v3 < v) || (v3 == v && (k + 3) < pk);
            }
            for (; k < b; ++k) { float vj = win[k]; rank += (vj < v) || (vj == v && k < pk); }
        } else {
            int j = start;
            for (; j + 3 < end; j += 4) {
                float v0 = sx[j], v1 = sx[j + 1], v2 = sx[j + 2], v3 = sx[j + 3];
                rank += (v0 < v) || (v0 == v && (j)     < p);
                rank += (v1 < v) || (v1 == v && (j + 1) < p);
                rank += (v2 < v) || (v2 == v && (j + 2) < p);
                rank += (v3 < v) || (v3 == v && (j + 3) < p);
            }
            for (; j < end; ++j) { float vj = sx[j]; rank += (vj < v) || (vj == v && j < p); }
        }
        diff = fabsf(v - y[start + rank]);
    }

    // per-wave reduction keyed by segment (waves span >1 segment only at boundaries)
    int smin = s;
    for (int off = 32; off > 0; off >>= 1) smin = min(smin, __shfl_xor(smin, off));
    float part = (s == smin) ? diff : 0.f;
    for (int off = 32; off > 0; off >>= 1) part += __shfl_xor(part, off);
    int lane = tid & 63;
    if (lane == 0 && smin != INT_MAX) atomicAdd(&segSums[smin], part);
    if (s != smin && s != INT_MAX) atomicAdd(&segSums[s], diff);
}

// ---- 5. finalize: mean over segments of (sum/count) * strength ----
__global__ void k_final(const float* __restrict__ segSums, const int* __restrict__ seg_ends,
                        float* __restrict__ out) {
    __shared__ float red[256];
    int t = threadIdx.x;
    float acc = 0.f;
    for (int s = t; s < NSEG; s += 256) {
        int end = seg_ends[s];
        int st = (s == 0) ? 0 : seg_ends[s - 1];
        float cnt = (float)(end - st);
        acc += segSums[s] / fmaxf(cnt, 1.0f);
    }
    red[t] = acc;
    __syncthreads();
    for (int off = 128; off > 0; off >>= 1) {
        if (t < off) red[t] += red[t + off];
        __syncthreads();
    }
    if (t == 0) out[0] = red[0] * (1.0f / (float)NSEG) * STRENGTH;
}

extern "C" void kernel_launch(void* const* d_in, const int* in_sizes, int n_in,
                              void* d_out, int out_size, void* d_ws, size_t ws_size,
                              hipStream_t stream) {
    const float* x = (const float*)d_in[0];
    const float* y = (const float*)d_in[1];          // initial_sorted
    const int* seg = (const int*)d_in[2];            // segment_ids (sorted)
    int N = in_sizes[0];

    // pick bucket count per segment to fit workspace
    int B = 8192;
    while (B > 64) {
        size_t need = (size_t)N * 4 + 2ull * NSEG * B * 4 + 1024 * 4 + NSEG * 8 + 256;
        if (need <= ws_size) break;
        B >>= 1;
    }
    int M = NSEG * B;
    float scale = (float)B / 12.0f;

    char* ws = (char*)d_ws;
    float* sx       = (float*)ws;                         // N floats
    int*   counts   = (int*)(ws + (size_t)N * 4);         // M ints
    int*   cursor   = counts + M;                         // M ints (starts -> ends)
    int*   partials = cursor + M;                         // <=1024 ints
    float* segSums  = (float*)(partials + 1024);          // NSEG floats
    int*   seg_ends = (int*)(segSums + NSEG);             // NSEG ints

    hipMemsetAsync(counts, 0, (size_t)M * 4, stream);
    hipMemsetAsync(segSums, 0, NSEG * 4, stream);

    int nb = (M + 2047) / 2048;
    k_hist<<<2048, 256, 0, stream>>>(x, seg, counts, N, B, scale);
    k_scan_partial<<<nb, 256, 0, stream>>>(counts, partials, M);
    k_scan_carry<<<1, 1024, 0, stream>>>(partials, nb);
    k_scan_final<<<nb, 256, 0, stream>>>(counts, partials, cursor, M);
    k_scatter<<<2048, 256, 0, stream>>>(x, seg, cursor, sx, N, B, scale);
    k_segends<<<1, 256, 0, stream>>>(cursor, seg_ends, B);
    k_emd<<<(N + 255) / 256, 256, 0, stream>>>(sx, y, cursor, seg_ends, segSums, N, B, scale);
    k_final<<<1, 256, 0, stream>>>(segSums, seg_ends, (float*)d_out);
}

// Round 3
// 251.679 us; speedup vs baseline: 7.1111x; 7.1111x over previous
//
#include <hip/hip_runtime.h>
#include <hip/hip_bf16.h>
#include <limits.h>

#define NSEG 200
#define STRENGTH 1e-3f
#define NB 2048                 // buckets per segment (compile-time)
#define M_TOT (NSEG * NB)
#define HCHUNK 8192             // elements per hist/scatter block
#define ECHUNK 2048             // elements per emd block
#define WCAP 2560               // LDS window capacity; max needed = ECHUNK + 2*max_bucket (~2250)

__device__ __forceinline__ int bucket_of(float x, float scale) {
    float t = (x + 6.0f) * scale;   // scale = NB/12
    int b = (int)floorf(t);
    b = b < 0 ? 0 : (b > NB - 1 ? NB - 1 : b);
    return b;
}

// ---- 0. segment boundaries from sorted seg ids ----
__global__ void k_bounds(const int* __restrict__ seg, int* __restrict__ seg_starts, int N) {
    int stride = gridDim.x * blockDim.x;
    int tid = blockIdx.x * blockDim.x + threadIdx.x;
    if (tid == 0) { seg_starts[0] = 0; seg_starts[NSEG] = N; }
    const int4* s4 = (const int4*)seg;
    int N4 = N >> 2;
    for (int i = tid; i < N4; i += stride) {
        int4 s = s4[i];
        int prev = (i == 0) ? s.x : seg[i * 4 - 1];
        if (s.x != prev) seg_starts[s.x] = i * 4;
        if (s.y != s.x) seg_starts[s.y] = i * 4 + 1;
        if (s.z != s.y) seg_starts[s.z] = i * 4 + 2;
        if (s.w != s.z) seg_starts[s.w] = i * 4 + 3;
    }
}

// ---- 1. histogram of (segment, bucket) via per-block LDS hist ----
__global__ void __launch_bounds__(512)
k_hist(const float* __restrict__ x, const int* __restrict__ seg_starts,
       int* __restrict__ counts, int N, float scale) {
    __shared__ int h[2 * NB];
    __shared__ int sst[NSEG + 1];
    int t = threadIdx.x;
    for (int k = t; k < NSEG + 1; k += 512) sst[k] = seg_starts[k];
    for (int k = t; k < 2 * NB; k += 512) h[k] = 0;
    __syncthreads();
    int base = blockIdx.x * HCHUNK;
    int lo = 0, hi = NSEG - 1;
    while (lo < hi) { int mid = (lo + hi) >> 1; if (base < sst[mid + 1]) hi = mid; else lo = mid + 1; }
    int s0 = lo, bnd = sst[lo + 1];
    const float4* x4 = (const float4*)x;
    for (int it = 0; it < HCHUNK / (512 * 4); ++it) {
        int j = (it * 512 + t) * 4;
        int gi = base + j;
        if (gi < N) {
            float4 v = x4[(base >> 2) + it * 512 + t];
            int sel0 = (gi + 0) >= bnd ? NB : 0;
            int sel1 = (gi + 1) >= bnd ? NB : 0;
            int sel2 = (gi + 2) >= bnd ? NB : 0;
            int sel3 = (gi + 3) >= bnd ? NB : 0;
            atomicAdd(&h[sel0 + bucket_of(v.x, scale)], 1);
            atomicAdd(&h[sel1 + bucket_of(v.y, scale)], 1);
            atomicAdd(&h[sel2 + bucket_of(v.z, scale)], 1);
            atomicAdd(&h[sel3 + bucket_of(v.w, scale)], 1);
        }
    }
    __syncthreads();
    for (int k = t; k < 2 * NB; k += 512) {
        int c = h[k];
        if (c > 0) atomicAdd(&counts[(s0 + (k >= NB)) * NB + (k & (NB - 1))], c);
    }
}

// ---- 2. exclusive scan over M_TOT counters ----
__global__ void k_scan_partial(const int* __restrict__ counts, int* __restrict__ partials, int M) {
    __shared__ int sdata[256];
    int base = blockIdx.x * 2048;
    int sum = 0;
    for (int k = threadIdx.x; k < 2048; k += 256) {
        int idx = base + k;
        sum += (idx < M) ? counts[idx] : 0;
    }
    sdata[threadIdx.x] = sum;
    __syncthreads();
    for (int off = 128; off > 0; off >>= 1) {
        if (threadIdx.x < off) sdata[threadIdx.x] += sdata[threadIdx.x + off];
        __syncthreads();
    }
    if (threadIdx.x == 0) partials[blockIdx.x] = sdata[0];
}

__global__ void k_scan_carry(int* __restrict__ partials, int nb) {
    __shared__ int bufA[1024], bufB[1024];
    int t = threadIdx.x;
    int v = (t < nb) ? partials[t] : 0;
    int* src = bufA; int* dst = bufB;
    src[t] = v;
    __syncthreads();
    for (int off = 1; off < 1024; off <<= 1) {
        dst[t] = src[t] + ((t >= off) ? src[t - off] : 0);
        __syncthreads();
        int* tmp = src; src = dst; dst = tmp;
    }
    if (t < nb) partials[t] = src[t] - v;   // exclusive
}

__global__ void k_scan_final(const int* __restrict__ counts, const int* __restrict__ partials,
                             int* __restrict__ cursor, int M) {
    __shared__ int tile[2048];
    __shared__ int sa[256], sb[256];
    int t = threadIdx.x;
    int base = blockIdx.x * 2048;
    for (int k = t; k < 2048; k += 256) {
        int idx = base + k;
        tile[k] = (idx < M) ? counts[idx] : 0;
    }
    __syncthreads();
    int loc[8]; int run = 0;
    for (int k = 0; k < 8; ++k) { loc[k] = run; run += tile[t * 8 + k]; }
    int v = run;
    int* src = sa; int* dst = sb;
    src[t] = v;
    __syncthreads();
    for (int off = 1; off < 256; off <<= 1) {
        dst[t] = src[t] + ((t >= off) ? src[t - off] : 0);
        __syncthreads();
        int* tmp = src; src = dst; dst = tmp;
    }
    int texcl = src[t] - v;
    int gbase = partials[blockIdx.x];
    for (int k = 0; k < 8; ++k) {
        int idx = base + t * 8 + k;
        if (idx < M) cursor[idx] = gbase + texcl + loc[k];
    }
}

// ---- 3. scatter with per-block reservation (cursor: starts -> ends) ----
__global__ void __launch_bounds__(512)
k_scatter(const float* __restrict__ x, const int* __restrict__ seg_starts,
          int* __restrict__ cursor, float* __restrict__ sx, int N, float scale) {
    __shared__ int h[2 * NB];
    __shared__ unsigned short lr[HCHUNK];
    __shared__ int sst[NSEG + 1];
    int t = threadIdx.x;
    for (int k = t; k < NSEG + 1; k += 512) sst[k] = seg_starts[k];
    for (int k = t; k < 2 * NB; k += 512) h[k] = 0;
    __syncthreads();
    int base = blockIdx.x * HCHUNK;
    int lo = 0, hi = NSEG - 1;
    while (lo < hi) { int mid = (lo + hi) >> 1; if (base < sst[mid + 1]) hi = mid; else lo = mid + 1; }
    int s0 = lo, bnd = sst[lo + 1];
    const float4* x4 = (const float4*)x;
    // pass 1: local ranks
    for (int it = 0; it < HCHUNK / (512 * 4); ++it) {
        int j = (it * 512 + t) * 4;
        int gi = base + j;
        if (gi < N) {
            float4 v = x4[(base >> 2) + it * 512 + t];
            int g0 = ((gi + 0) >= bnd ? NB : 0) + bucket_of(v.x, scale);
            int g1 = ((gi + 1) >= bnd ? NB : 0) + bucket_of(v.y, scale);
            int g2 = ((gi + 2) >= bnd ? NB : 0) + bucket_of(v.z, scale);
            int g3 = ((gi + 3) >= bnd ? NB : 0) + bucket_of(v.w, scale);
            lr[j + 0] = (unsigned short)atomicAdd(&h[g0], 1);
            lr[j + 1] = (unsigned short)atomicAdd(&h[g1], 1);
            lr[j + 2] = (unsigned short)atomicAdd(&h[g2], 1);
            lr[j + 3] = (unsigned short)atomicAdd(&h[g3], 1);
        }
    }
    __syncthreads();
    // reserve: h[k] becomes global base for this block's (seg,bucket) group
    for (int k = t; k < 2 * NB; k += 512) {
        int c = h[k];
        if (c > 0) h[k] = atomicAdd(&cursor[(s0 + (k >= NB)) * NB + (k & (NB - 1))], c);
    }
    __syncthreads();
    // pass 2: write
    for (int it = 0; it < HCHUNK / (512 * 4); ++it) {
        int j = (it * 512 + t) * 4;
        int gi = base + j;
        if (gi < N) {
            float4 v = x4[(base >> 2) + it * 512 + t];
            int g0 = ((gi + 0) >= bnd ? NB : 0) + bucket_of(v.x, scale);
            int g1 = ((gi + 1) >= bnd ? NB : 0) + bucket_of(v.y, scale);
            int g2 = ((gi + 2) >= bnd ? NB : 0) + bucket_of(v.z, scale);
            int g3 = ((gi + 3) >= bnd ? NB : 0) + bucket_of(v.w, scale);
            sx[h[g0] + lr[j + 0]] = v.x;
            sx[h[g1] + lr[j + 1]] = v.y;
            sx[h[g2] + lr[j + 2]] = v.z;
            sx[h[g3] + lr[j + 3]] = v.w;
        }
    }
}

// ---- 3b. per-segment end positions ----
__global__ void k_segends(const int* __restrict__ ends, int* __restrict__ seg_ends) {
    int t = blockIdx.x * blockDim.x + threadIdx.x;
    if (t < NSEG) seg_ends[t] = ends[(t + 1) * NB - 1];
}

// ---- 4. rank within bucket via LDS windows (sx AND y) ----
__global__ void __launch_bounds__(256)
k_emd(const float* __restrict__ sx, const float* __restrict__ y,
      const int* __restrict__ ends, const int* __restrict__ seg_ends,
      float* __restrict__ segSums, int N, float scale) {
    __shared__ float win[WCAP];
    __shared__ float ywin[WCAP];
    __shared__ int sEnd[NSEG];
    __shared__ int sh[4];       // wlo, whi, s0
    int tid = threadIdx.x;
    for (int k = tid; k < NSEG; k += 256) sEnd[k] = seg_ends[k];
    __syncthreads();
    int pbase = blockIdx.x * ECHUNK;
    int pend = min(pbase + ECHUNK, N);
    if (tid == 0) {
        float v = sx[pbase];
        int lo = 0, hi = NSEG - 1;
        while (lo < hi) { int mid = (lo + hi) >> 1; if (pbase < sEnd[mid]) hi = mid; else lo = mid + 1; }
        int g = lo * NB + bucket_of(v, scale);
        sh[0] = (g == 0) ? 0 : ends[g - 1];
        sh[2] = lo;
    }
    if (tid == 255) {
        float v = sx[pend - 1];
        int lo = 0, hi = NSEG - 1;
        while (lo < hi) { int mid = (lo + hi) >> 1; if (pend - 1 < sEnd[mid]) hi = mid; else lo = mid + 1; }
        sh[1] = ends[lo * NB + bucket_of(v, scale)];
    }
    __syncthreads();
    int wlo = sh[0], whi = sh[1], s0 = sh[2];
    bool useLds = (whi - wlo) <= WCAP;
    if (useLds) {
        for (int k = tid; k < whi - wlo; k += 256) { win[k] = sx[wlo + k]; ywin[k] = y[wlo + k]; }
    }
    __syncthreads();

    float acc0 = 0.f, acc1 = 0.f;
    for (int e = 0; e < ECHUNK / 256; ++e) {
        int p = pbase + (e << 8) + tid;
        if (p >= pend) break;
        int s = s0;
        while (p >= sEnd[s]) ++s;
        float v = useLds ? win[p - wlo] : sx[p];
        int g = s * NB + bucket_of(v, scale);
        int start = (g == 0) ? 0 : ends[g - 1];
        int end = ends[g];
        int rank = 0;
        float diff;
        if (useLds) {
            int a = start - wlo, b = end - wlo, pk = p - wlo;
            int k = a;
            for (; k + 3 < b; k += 4) {
                float v0 = win[k], v1 = win[k + 1], v2 = win[k + 2], v3 = win[k + 3];
                rank += (v0 < v) || (v0 == v && (k)     < pk);
                rank += (v1 < v) || (v1 == v && (k + 1) < pk);
                rank += (v2 < v) || (v2 == v && (k + 2) < pk);
                rank += (v3 < v) || (v3 == v && (k + 3) < pk);
            }
            for (; k < b; ++k) { float vj = win[k]; rank += (vj < v) || (vj == v && k < pk); }
            diff = fabsf(v - ywin[a + rank]);
        } else {
            for (int j = start; j < end; ++j) { float vj = sx[j]; rank += (vj < v) || (vj == v && j < p); }
            diff = fabsf(v - y[start + rank]);
        }
        if (s == s0) acc0 += diff;
        else if (s == s0 + 1) acc1 += diff;
        else atomicAdd(&segSums[s], diff);
    }
    for (int off = 32; off > 0; off >>= 1) {
        acc0 += __shfl_xor(acc0, off);
        acc1 += __shfl_xor(acc1, off);
    }
    if ((tid & 63) == 0) {
        if (acc0 != 0.f) atomicAdd(&segSums[s0], acc0);
        if (acc1 != 0.f && s0 + 1 < NSEG) atomicAdd(&segSums[s0 + 1], acc1);
    }
}

// ---- 5. finalize ----
__global__ void k_final(const float* __restrict__ segSums, const int* __restrict__ seg_ends,
                        float* __restrict__ out) {
    __shared__ float red[256];
    int t = threadIdx.x;
    float acc = 0.f;
    for (int s = t; s < NSEG; s += 256) {
        int end = seg_ends[s];
        int st = (s == 0) ? 0 : seg_ends[s - 1];
        float cnt = (float)(end - st);
        acc += segSums[s] / fmaxf(cnt, 1.0f);
    }
    red[t] = acc;
    __syncthreads();
    for (int off = 128; off > 0; off >>= 1) {
        if (t < off) red[t] += red[t + off];
        __syncthreads();
    }
    if (t == 0) out[0] = red[0] * (1.0f / (float)NSEG) * STRENGTH;
}

extern "C" void kernel_launch(void* const* d_in, const int* in_sizes, int n_in,
                              void* d_out, int out_size, void* d_ws, size_t ws_size,
                              hipStream_t stream) {
    const float* x = (const float*)d_in[0];
    const float* y = (const float*)d_in[1];          // initial_sorted
    const int* seg = (const int*)d_in[2];            // segment_ids (sorted)
    int N = in_sizes[0];
    float scale = (float)NB / 12.0f;

    char* ws = (char*)d_ws;
    float* sx        = (float*)ws;                        // N floats
    int*   counts    = (int*)(ws + (size_t)N * 4);        // M_TOT ints
    int*   cursor    = counts + M_TOT;                    // M_TOT ints
    int*   partials  = cursor + M_TOT;                    // <=1024 ints
    float* segSums   = (float*)(partials + 1024);         // NSEG floats
    int*   seg_ends  = (int*)(segSums + NSEG);            // NSEG ints
    int*   seg_starts= seg_ends + NSEG;                   // NSEG+1 ints

    hipMemsetAsync(counts, 0, (size_t)M_TOT * 4, stream);
    hipMemsetAsync(segSums, 0, NSEG * 4, stream);

    int nb = (M_TOT + 2047) / 2048;    // = 200
    int nchunk = (N + HCHUNK - 1) / HCHUNK;

    k_bounds<<<256, 256, 0, stream>>>(seg, seg_starts, N);
    k_hist<<<nchunk, 512, 0, stream>>>(x, seg_starts, counts, N, scale);
    k_scan_partial<<<nb, 256, 0, stream>>>(counts, partials, M_TOT);
    k_scan_carry<<<1, 1024, 0, stream>>>(partials, nb);
    k_scan_final<<<nb, 256, 0, stream>>>(counts, partials, cursor, M_TOT);
    k_scatter<<<nchunk, 512, 0, stream>>>(x, seg_starts, cursor, sx, N, scale);
    k_segends<<<1, 256, 0, stream>>>(cursor, seg_ends);
    k_emd<<<(N + ECHUNK - 1) / ECHUNK, 256, 0, stream>>>(sx, y, cursor, seg_ends, segSums, N, scale);
    k_final<<<1, 256, 0, stream>>>(segSums, seg_ends, (float*)d_out);
}

// Round 4
// 251.384 us; speedup vs baseline: 7.1194x; 1.0012x over previous
//
#include <hip/hip_runtime.h>
#include <hip/hip_bf16.h>
#include <limits.h>

#define NSEG 200
#define STRENGTH 1e-3f
#define NB 2048                 // coarse buckets per segment
#define M_TOT (NSEG * NB)
#define HCHUNK 8192             // elements per hist/scatter block
#define ECHUNK 2048             // elements per emd block
#define WCAP 2560               // LDS window capacity (ECHUNK + 2*max_bucket)
#define FBINS 8192              // fine bins per emd block (16 sub-bins/coarse)
#define FWORDS (FBINS / 2 + 1)  // packed u16 prefix words (+ sentinel)

__device__ __forceinline__ int bucket_of(float x, float scale) {
    float t = (x + 6.0f) * scale;   // scale = NB/12
    int b = (int)floorf(t);
    b = b < 0 ? 0 : (b > NB - 1 ? NB - 1 : b);
    return b;
}

// ---- 0. segment boundaries from sorted seg ids ----
__global__ void k_bounds(const int* __restrict__ seg, int* __restrict__ seg_starts, int N) {
    int stride = gridDim.x * blockDim.x;
    int tid = blockIdx.x * blockDim.x + threadIdx.x;
    if (tid == 0) { seg_starts[0] = 0; seg_starts[NSEG] = N; }
    const int4* s4 = (const int4*)seg;
    int N4 = N >> 2;
    for (int i = tid; i < N4; i += stride) {
        int4 s = s4[i];
        int prev = (i == 0) ? s.x : seg[i * 4 - 1];
        if (s.x != prev) seg_starts[s.x] = i * 4;
        if (s.y != s.x) seg_starts[s.y] = i * 4 + 1;
        if (s.z != s.y) seg_starts[s.z] = i * 4 + 2;
        if (s.w != s.z) seg_starts[s.w] = i * 4 + 3;
    }
}

// ---- 1. histogram of (segment, bucket) via per-block LDS hist ----
__global__ void __launch_bounds__(512)
k_hist(const float* __restrict__ x, const int* __restrict__ seg_starts,
       int* __restrict__ counts, int N, float scale) {
    __shared__ int h[2 * NB];
    __shared__ int sst[NSEG + 1];
    int t = threadIdx.x;
    for (int k = t; k < NSEG + 1; k += 512) sst[k] = seg_starts[k];
    for (int k = t; k < 2 * NB; k += 512) h[k] = 0;
    __syncthreads();
    int base = blockIdx.x * HCHUNK;
    int lo = 0, hi = NSEG - 1;
    while (lo < hi) { int mid = (lo + hi) >> 1; if (base < sst[mid + 1]) hi = mid; else lo = mid + 1; }
    int s0 = lo, bnd = sst[lo + 1];
    const float4* x4 = (const float4*)x;
    for (int it = 0; it < HCHUNK / (512 * 4); ++it) {
        int j = (it * 512 + t) * 4;
        int gi = base + j;
        if (gi < N) {
            float4 v = x4[(base >> 2) + it * 512 + t];
            int sel0 = (gi + 0) >= bnd ? NB : 0;
            int sel1 = (gi + 1) >= bnd ? NB : 0;
            int sel2 = (gi + 2) >= bnd ? NB : 0;
            int sel3 = (gi + 3) >= bnd ? NB : 0;
            atomicAdd(&h[sel0 + bucket_of(v.x, scale)], 1);
            atomicAdd(&h[sel1 + bucket_of(v.y, scale)], 1);
            atomicAdd(&h[sel2 + bucket_of(v.z, scale)], 1);
            atomicAdd(&h[sel3 + bucket_of(v.w, scale)], 1);
        }
    }
    __syncthreads();
    for (int k = t; k < 2 * NB; k += 512) {
        int c = h[k];
        if (c > 0) atomicAdd(&counts[(s0 + (k >= NB)) * NB + (k & (NB - 1))], c);
    }
}

// ---- 2. exclusive scan over M_TOT counters ----
__global__ void k_scan_partial(const int* __restrict__ counts, int* __restrict__ partials, int M) {
    __shared__ int sdata[256];
    int base = blockIdx.x * 2048;
    int sum = 0;
    for (int k = threadIdx.x; k < 2048; k += 256) {
        int idx = base + k;
        sum += (idx < M) ? counts[idx] : 0;
    }
    sdata[threadIdx.x] = sum;
    __syncthreads();
    for (int off = 128; off > 0; off >>= 1) {
        if (threadIdx.x < off) sdata[threadIdx.x] += sdata[threadIdx.x + off];
        __syncthreads();
    }
    if (threadIdx.x == 0) partials[blockIdx.x] = sdata[0];
}

__global__ void k_scan_carry(int* __restrict__ partials, int nb) {
    __shared__ int bufA[1024], bufB[1024];
    int t = threadIdx.x;
    int v = (t < nb) ? partials[t] : 0;
    int* src = bufA; int* dst = bufB;
    src[t] = v;
    __syncthreads();
    for (int off = 1; off < 1024; off <<= 1) {
        dst[t] = src[t] + ((t >= off) ? src[t - off] : 0);
        __syncthreads();
        int* tmp = src; src = dst; dst = tmp;
    }
    if (t < nb) partials[t] = src[t] - v;   // exclusive
}

__global__ void k_scan_final(const int* __restrict__ counts, const int* __restrict__ partials,
                             int* __restrict__ cursor, int M) {
    __shared__ int tile[2048];
    __shared__ int sa[256], sb[256];
    int t = threadIdx.x;
    int base = blockIdx.x * 2048;
    for (int k = t; k < 2048; k += 256) {
        int idx = base + k;
        tile[k] = (idx < M) ? counts[idx] : 0;
    }
    __syncthreads();
    int loc[8]; int run = 0;
    for (int k = 0; k < 8; ++k) { loc[k] = run; run += tile[t * 8 + k]; }
    int v = run;
    int* src = sa; int* dst = sb;
    src[t] = v;
    __syncthreads();
    for (int off = 1; off < 256; off <<= 1) {
        dst[t] = src[t] + ((t >= off) ? src[t - off] : 0);
        __syncthreads();
        int* tmp = src; src = dst; dst = tmp;
    }
    int texcl = src[t] - v;
    int gbase = partials[blockIdx.x];
    for (int k = 0; k < 8; ++k) {
        int idx = base + t * 8 + k;
        if (idx < M) cursor[idx] = gbase + texcl + loc[k];
    }
}

// ---- 3. scatter with per-block reservation (cursor: starts -> ends) ----
__global__ void __launch_bounds__(512)
k_scatter(const float* __restrict__ x, const int* __restrict__ seg_starts,
          int* __restrict__ cursor, float* __restrict__ sx, int N, float scale) {
    __shared__ int h[2 * NB];
    __shared__ unsigned short lr[HCHUNK];
    __shared__ int sst[NSEG + 1];
    int t = threadIdx.x;
    for (int k = t; k < NSEG + 1; k += 512) sst[k] = seg_starts[k];
    for (int k = t; k < 2 * NB; k += 512) h[k] = 0;
    __syncthreads();
    int base = blockIdx.x * HCHUNK;
    int lo = 0, hi = NSEG - 1;
    while (lo < hi) { int mid = (lo + hi) >> 1; if (base < sst[mid + 1]) hi = mid; else lo = mid + 1; }
    int s0 = lo, bnd = sst[lo + 1];
    const float4* x4 = (const float4*)x;
    // pass 1: local ranks
    for (int it = 0; it < HCHUNK / (512 * 4); ++it) {
        int j = (it * 512 + t) * 4;
        int gi = base + j;
        if (gi < N) {
            float4 v = x4[(base >> 2) + it * 512 + t];
            int g0 = ((gi + 0) >= bnd ? NB : 0) + bucket_of(v.x, scale);
            int g1 = ((gi + 1) >= bnd ? NB : 0) + bucket_of(v.y, scale);
            int g2 = ((gi + 2) >= bnd ? NB : 0) + bucket_of(v.z, scale);
            int g3 = ((gi + 3) >= bnd ? NB : 0) + bucket_of(v.w, scale);
            lr[j + 0] = (unsigned short)atomicAdd(&h[g0], 1);
            lr[j + 1] = (unsigned short)atomicAdd(&h[g1], 1);
            lr[j + 2] = (unsigned short)atomicAdd(&h[g2], 1);
            lr[j + 3] = (unsigned short)atomicAdd(&h[g3], 1);
        }
    }
    __syncthreads();
    // reserve: h[k] becomes global base for this block's (seg,bucket) group
    for (int k = t; k < 2 * NB; k += 512) {
        int c = h[k];
        if (c > 0) h[k] = atomicAdd(&cursor[(s0 + (k >= NB)) * NB + (k & (NB - 1))], c);
    }
    __syncthreads();
    // pass 2: write
    for (int it = 0; it < HCHUNK / (512 * 4); ++it) {
        int j = (it * 512 + t) * 4;
        int gi = base + j;
        if (gi < N) {
            float4 v = x4[(base >> 2) + it * 512 + t];
            int g0 = ((gi + 0) >= bnd ? NB : 0) + bucket_of(v.x, scale);
            int g1 = ((gi + 1) >= bnd ? NB : 0) + bucket_of(v.y, scale);
            int g2 = ((gi + 2) >= bnd ? NB : 0) + bucket_of(v.z, scale);
            int g3 = ((gi + 3) >= bnd ? NB : 0) + bucket_of(v.w, scale);
            sx[h[g0] + lr[j + 0]] = v.x;
            sx[h[g1] + lr[j + 1]] = v.y;
            sx[h[g2] + lr[j + 2]] = v.z;
            sx[h[g3] + lr[j + 3]] = v.w;
        }
    }
}

// ---- 3b. per-segment end positions ----
__global__ void k_segends(const int* __restrict__ ends, int* __restrict__ seg_ends) {
    int t = blockIdx.x * blockDim.x + threadIdx.x;
    if (t < NSEG) seg_ends[t] = ends[(t + 1) * NB - 1];
}

// ---- 4. rank within bucket: fine-bin counting-sort refinement in LDS ----
__global__ void __launch_bounds__(256)
k_emd(const float* __restrict__ sx, const float* __restrict__ y,
      const int* __restrict__ ends, const int* __restrict__ seg_ends,
      float* __restrict__ segSums, int N, float scale, float scalef) {
    __shared__ float win[WCAP];
    __shared__ unsigned int fh[FWORDS];       // packed u16 counts -> exclusive prefix
    __shared__ unsigned short perm[WCAP];     // window indices sorted by fine bin
    __shared__ int sEnd[NSEG];
    __shared__ int sh[5];
    __shared__ unsigned int tsA[256], tsB[256];
    int tid = threadIdx.x;
    for (int k = tid; k < NSEG; k += 256) sEnd[k] = seg_ends[k];
    __syncthreads();
    int pbase = blockIdx.x * ECHUNK;
    int pend = min(pbase + ECHUNK, N);
    if (tid == 0) {
        float v = sx[pbase];
        int lo = 0, hi = NSEG - 1;
        while (lo < hi) { int mid = (lo + hi) >> 1; if (pbase < sEnd[mid]) hi = mid; else lo = mid + 1; }
        int g = lo * NB + bucket_of(v, scale);
        sh[0] = (g == 0) ? 0 : ends[g - 1];
        sh[2] = lo;
        sh[3] = g;
    }
    if (tid == 255) {
        float v = sx[pend - 1];
        int lo = 0, hi = NSEG - 1;
        while (lo < hi) { int mid = (lo + hi) >> 1; if (pend - 1 < sEnd[mid]) hi = mid; else lo = mid + 1; }
        int g = lo * NB + bucket_of(v, scale);
        sh[1] = ends[g];
        sh[4] = g;
    }
    __syncthreads();
    int wlo = sh[0], whi = sh[1], s0 = sh[2], gfirst = sh[3], glast = sh[4];
    int wsz = whi - wlo;
    int bnd0 = sEnd[s0];
    bool fits = wsz <= WCAP;
    bool fine = fits && (glast - gfirst) < (FBINS >> 4);
    if (fits) {
        for (int k = tid; k < wsz; k += 256) win[k] = sx[wlo + k];
    }
    if (fine) {
        for (int k = tid; k < FWORDS; k += 256) fh[k] = 0;
    }
    __syncthreads();

    float acc0 = 0.f, acc1 = 0.f;

    if (fine) {
        // (a) fine histogram of ALL window elements (packed u16 atomics)
        int lfr[10], llo[10];
        #pragma unroll
        for (int i = 0; i < 10; ++i) {
            int k = tid + i * 256;
            lfr[i] = -1;
            if (k < wsz) {
                float v = win[k];
                int pos = wlo + k;
                int s = s0 + (pos >= bnd0 ? 1 : 0);
                int b = bucket_of(v, scale);
                int fsub = (int)floorf((v + 6.0f) * scalef) - (b << 4);
                fsub = fsub < 0 ? 0 : (fsub > 15 ? 15 : fsub);
                int fr = ((s * NB + b) - gfirst) * 16 + fsub;
                lfr[i] = fr;
                unsigned sh16 = (fr & 1) << 4;
                llo[i] = (int)((atomicAdd(&fh[fr >> 1], 1u << sh16) >> sh16) & 0xFFFFu);
            }
        }
        __syncthreads();
        // (b) counts -> exclusive prefix in place
        unsigned wbuf[16];
        unsigned run = 0;
        #pragma unroll
        for (int i = 0; i < 16; ++i) {
            unsigned w = fh[tid * 16 + i];
            unsigned c0 = w & 0xFFFFu, c1 = w >> 16;
            wbuf[i] = run | ((run + c0) << 16);
            run += c0 + c1;
        }
        tsA[tid] = run;
        __syncthreads();
        unsigned* src = tsA; unsigned* dst = tsB;
        for (int off = 1; off < 256; off <<= 1) {
            unsigned v = src[tid] + ((tid >= off) ? src[tid - off] : 0);
            dst[tid] = v;
            __syncthreads();
            unsigned* tmp = src; src = dst; dst = tmp;
        }
        unsigned base = src[tid] - run;         // exclusive block prefix
        unsigned total = src[255];
        #pragma unroll
        for (int i = 0; i < 16; ++i)
            fh[tid * 16 + i] = wbuf[i] + (base | (base << 16));
        if (tid == 255) fh[FBINS / 2] = total;  // sentinel (bin 8192, low half)
        __syncthreads();
        // (c) counting-sort scatter of window indices
        #pragma unroll
        for (int i = 0; i < 10; ++i) {
            if (lfr[i] >= 0) {
                int fr = lfr[i];
                unsigned pfx = (fh[fr >> 1] >> ((fr & 1) << 4)) & 0xFFFFu;
                perm[pfx + (unsigned)llo[i]] = (unsigned short)(tid + i * 256);
            }
        }
        __syncthreads();
        // (d) rank = cross-fine-bin prefix + tie scan within own fine bin
        for (int e = 0; e < ECHUNK / 256; ++e) {
            int p = pbase + (e << 8) + tid;
            if (p >= pend) break;
            int widx = p - wlo;
            float v = win[widx];
            int s = s0 + (p >= bnd0 ? 1 : 0);
            int b = bucket_of(v, scale);
            int g = s * NB + b;
            int fsub = (int)floorf((v + 6.0f) * scalef) - (b << 4);
            fsub = fsub < 0 ? 0 : (fsub > 15 ? 15 : fsub);
            int fr = (g - gfirst) * 16 + fsub;
            int fb0 = (g - gfirst) * 16;
            unsigned pf_f = (fh[fr >> 1] >> ((fr & 1) << 4)) & 0xFFFFu;
            unsigned pf_b = fh[fb0 >> 1] & 0xFFFFu;                 // fb0 even
            unsigned pf_n = (fh[(fr + 1) >> 1] >> (((fr + 1) & 1) << 4)) & 0xFFFFu;
            int rank = (int)(pf_f - pf_b);
            for (unsigned j = pf_f; j < pf_n; ++j) {
                int pj = perm[j];
                float u = win[pj];
                rank += (u < v) || (u == v && pj < widx);
            }
            int start = (g == 0) ? 0 : ends[g - 1];
            float diff = fabsf(v - y[start + rank]);
            if (s == s0) acc0 += diff; else acc1 += diff;
        }
    } else if (fits) {
        // direct LDS scan (wide-span windows: tails / boundary blocks — small buckets)
        for (int e = 0; e < ECHUNK / 256; ++e) {
            int p = pbase + (e << 8) + tid;
            if (p >= pend) break;
            int s = s0;
            while (p >= sEnd[s]) ++s;
            int widx = p - wlo;
            float v = win[widx];
            int g = s * NB + bucket_of(v, scale);
            int start = (g == 0) ? 0 : ends[g - 1];
            int end = ends[g];
            int a = start - wlo, bq = end - wlo;
            int rank = 0;
            int k = a;
            for (; k + 3 < bq; k += 4) {
                float v0 = win[k], v1 = win[k + 1], v2 = win[k + 2], v3 = win[k + 3];
                rank += (v0 < v) || (v0 == v && (k)     < widx);
                rank += (v1 < v) || (v1 == v && (k + 1) < widx);
                rank += (v2 < v) || (v2 == v && (k + 2) < widx);
                rank += (v3 < v) || (v3 == v && (k + 3) < widx);
            }
            for (; k < bq; ++k) { float vj = win[k]; rank += (vj < v) || (vj == v && k < widx); }
            float diff = fabsf(v - y[start + rank]);
            if (s == s0) acc0 += diff;
            else if (s == s0 + 1) acc1 += diff;
            else atomicAdd(&segSums[s], diff);
        }
    } else {
        // global fallback (window exceeds LDS — should not happen at these sizes)
        for (int e = 0; e < ECHUNK / 256; ++e) {
            int p = pbase + (e << 8) + tid;
            if (p >= pend) break;
            int s = s0;
            while (p >= sEnd[s]) ++s;
            float v = sx[p];
            int g = s * NB + bucket_of(v, scale);
            int start = (g == 0) ? 0 : ends[g - 1];
            int end = ends[g];
            int rank = 0;
            for (int j = start; j < end; ++j) { float vj = sx[j]; rank += (vj < v) || (vj == v && j < p); }
            float diff = fabsf(v - y[start + rank]);
            if (s == s0) acc0 += diff;
            else if (s == s0 + 1) acc1 += diff;
            else atomicAdd(&segSums[s], diff);
        }
    }

    for (int off = 32; off > 0; off >>= 1) {
        acc0 += __shfl_xor(acc0, off);
        acc1 += __shfl_xor(acc1, off);
    }
    if ((tid & 63) == 0) {
        if (acc0 != 0.f) atomicAdd(&segSums[s0], acc0);
        if (acc1 != 0.f && s0 + 1 < NSEG) atomicAdd(&segSums[s0 + 1], acc1);
    }
}

// ---- 5. finalize ----
__global__ void k_final(const float* __restrict__ segSums, const int* __restrict__ seg_ends,
                        float* __restrict__ out) {
    __shared__ float red[256];
    int t = threadIdx.x;
    float acc = 0.f;
    for (int s = t; s < NSEG; s += 256) {
        int end = seg_ends[s];
        int st = (s == 0) ? 0 : seg_ends[s - 1];
        float cnt = (float)(end - st);
        acc += segSums[s] / fmaxf(cnt, 1.0f);
    }
    red[t] = acc;
    __syncthreads();
    for (int off = 128; off > 0; off >>= 1) {
        if (t < off) red[t] += red[t + off];
        __syncthreads();
    }
    if (t == 0) out[0] = red[0] * (1.0f / (float)NSEG) * STRENGTH;
}

extern "C" void kernel_launch(void* const* d_in, const int* in_sizes, int n_in,
                              void* d_out, int out_size, void* d_ws, size_t ws_size,
                              hipStream_t stream) {
    const float* x = (const float*)d_in[0];
    const float* y = (const float*)d_in[1];          // initial_sorted
    const int* seg = (const int*)d_in[2];            // segment_ids (sorted)
    int N = in_sizes[0];
    float scale = (float)NB / 12.0f;
    float scalef = (float)(NB * 16) / 12.0f;

    char* ws = (char*)d_ws;
    float* sx        = (float*)ws;                        // N floats
    int*   counts    = (int*)(ws + (size_t)N * 4);        // M_TOT ints
    int*   cursor    = counts + M_TOT;                    // M_TOT ints
    int*   partials  = cursor + M_TOT;                    // <=1024 ints
    float* segSums   = (float*)(partials + 1024);         // NSEG floats
    int*   seg_ends  = (int*)(segSums + NSEG);            // NSEG ints
    int*   seg_starts= seg_ends + NSEG;                   // NSEG+1 ints

    hipMemsetAsync(counts, 0, (size_t)M_TOT * 4, stream);
    hipMemsetAsync(segSums, 0, NSEG * 4, stream);

    int nb = (M_TOT + 2047) / 2048;    // = 200
    int nchunk = (N + HCHUNK - 1) / HCHUNK;

    k_bounds<<<256, 256, 0, stream>>>(seg, seg_starts, N);
    k_hist<<<nchunk, 512, 0, stream>>>(x, seg_starts, counts, N, scale);
    k_scan_partial<<<nb, 256, 0, stream>>>(counts, partials, M_TOT);
    k_scan_carry<<<1, 1024, 0, stream>>>(partials, nb);
    k_scan_final<<<nb, 256, 0, stream>>>(counts, partials, cursor, M_TOT);
    k_scatter<<<nchunk, 512, 0, stream>>>(x, seg_starts, cursor, sx, N, scale);
    k_segends<<<1, 256, 0, stream>>>(cursor, seg_ends);
    k_emd<<<(N + ECHUNK - 1) / ECHUNK, 256, 0, stream>>>(sx, y, cursor, seg_ends, segSums, N, scale, scalef);
    k_final<<<1, 256, 0, stream>>>(segSums, seg_ends, (float*)d_out);
}